// Round 3
// baseline (146.376 us; speedup 1.0000x reference)
//
#include <hip/hip_runtime.h>
#include <math.h>

// Problem constants (from reference)
#define NDIM   8
#define NBINS  64
#define LOG_BETA   (-13.815510557964274f)  // log(1e-6)
#define LN2F       0.69314718055994531f
// mesh is geometric: boundary_j (original coords) = x1L*(1.2^j-1)/0.2, j=0..32
// bin index from |x|: g = log2(1 + ALPHA*|x|) / log2(1.2);  ALPHA = (1.2^32-1)/10
#define ALPHA      34.0821892f
#define INV_LOG2R  3.80178401692393f       // 1/log2(1.2)
#define L2R        0.26303440583379378f    // log2(1.2)

typedef float f32x4 __attribute__((ext_vector_type(4)));  // ok for nontemporal builtins

// One thread per point (8 dims). All 4 iterations' loads are issued in the
// prologue (12 loads / 144 B per lane in flight) so the kernel is never
// latency-exposed: [issue all loads] -> [prep] -> [compute + nt-store] x4.
__global__ __launch_bounds__(256, 6) void cdfq_fused(const float* __restrict__ x,
                                                     const float* __restrict__ logdet_in,
                                                     const float* __restrict__ p,
                                                     float* __restrict__ y_out,
                                                     float* __restrict__ ld_out,
                                                     int n)
{
    __shared__ float4 stbl[NDIM * NBINS];  // [d][k]: {v1, slope, F_pre, mesh_k}

    const int t  = threadIdx.x;
    const int T  = gridDim.x * blockDim.x;         // threads total
    const int i0 = blockIdx.x * blockDim.x + t;
    const int iters = n / T;                       // points per thread (4 here)
    const bool fast = (iters == 4);
    const float4* xv4 = (const float4*)x;

    // ---- prologue: prefetch ALL fast-path iterations (issue order = use order)
    float4 Xa[4], Xb[4]; float Ld[4];
    if (fast) {
#pragma unroll
        for (int j = 0; j < 4; ++j) {
            int g = i0 + j * T;
            Xa[j] = xv4[2 * g];
            Xb[j] = xv4[2 * g + 1];
            Ld[j] = logdet_in[g];
        }
    }
    __builtin_amdgcn_sched_barrier(0);   // do not sink these below prep

    // ---- prep: each wave builds TWO dims of the table fully in-register.
    //      No mesh/elmt/pdfs LDS arrays, no powf, ONE barrier total. ----
    {
        const int lane = t & 63;
        const int w    = t >> 6;
        const float pw32 = exp2f(32.0f * L2R);     // 1.2^32
        const float inv  = 0.5f / (pw32 - 1.0f);
        auto meshf = [&](float tt) {               // normalized mesh coordinate
            float fidx = tt - 32.0f;
            float pw = exp2f(fabsf(fidx) * L2R);
            float r  = (pw - 1.0f) * inv;
            return 0.5f + ((fidx >= 0.0f) ? r : -r);
        };
        const float m0  = meshf((float)lane);          // mesh[lane]
        const float m1  = meshf((float)(lane + 1));    // mesh[lane+1]
        const float el  = m1 - m0;                     // elmt[lane]
        const float el1 = __shfl_down(el, 1);          // elmt[lane+1] (lane63 unused)
        const float e0e63 = 2.0f * (meshf(1.0f) - meshf(0.0f)); // elmt[0]+elmt[63]

#pragma unroll
        for (int dd = 0; dd < 2; ++dd) {
            const int d = 2 * w + dd;
            float ep = 0.0f;
            if (lane < 63) ep = __expf(p[lane * NDIM + d]);  // interior node lane+1
            // normalization: sum of ep * (elmt[k]+elmt[k+1])/2 over interior nodes
            float s = ep * 0.5f * (el + el1);
#pragma unroll
            for (int off = 32; off; off >>= 1) s += __shfl_xor(s, off);
            const float scale = (1.0f - e0e63 * 5e-7f) / s;
            const float epu = __shfl_up(ep, 1);
            const float pdl = (lane == 0)  ? 1e-6f : scale * epu;  // pdf[lane]
            const float pdn = (lane == 63) ? 1e-6f : scale * ep;   // pdf[lane+1]
            const float cell = 0.5f * (pdl + pdn) * el;
            // inclusive scan -> exclusive prefix
            float v = cell;
#pragma unroll
            for (int off = 1; off < 64; off <<= 1) {
                float u = __shfl_up(v, off);
                if (lane >= off) v += u;
            }
            stbl[(d << 6) | lane] = make_float4(pdl, (pdn - pdl) / el, v - cell, m0);
        }
    }
    __syncthreads();

    // ---- per-point body: all 8 dims in one thread, no cross-lane traffic ----
    auto body8 = [&](float4 A, float4 B, float Lin, int q) {
        float xd[8] = {A.x, A.y, A.z, A.w, B.x, B.y, B.z, B.w};
        float yd[8], dd8[8];
        float extra = 0.0f;

#pragma unroll
        for (int d = 0; d < 8; ++d) {
            float xo = xd[d];
            float xs = fmaf(xo, 0.05f, 0.5f);            // (x+10)/20 to 1 ulp
            // analytic bin: g = log2(1 + alpha*|x|)/log2(1.2); one v_log_f32
            float gg = __log2f(fmaf(ALPHA, fabsf(xo), 1.0f)) * INV_LOG2R;
            // merged index: CDF & derivative are continuous at bin boundaries,
            // so boundary misclassification (gg exactly integral) is harmless.
            int jf = (int)fminf(gg, 31.0f);
            int k  = (xo >= 0.0f) ? (32 + jf) : (31 - jf);

            float4 tb = stbl[(d << 6) + k];              // {v1, slope, F_pre, mesh_k}
            float xm  = xs - tb.w;
            bool cov  = (xs >= 0.0f) && (xs < 1.0f);

            float yc = tb.z + xm * fmaf(0.5f * xm, tb.y, tb.x);
            float dv = fmaf(xm, tb.y, tb.x);
            float yy = cov ? yc : xs;
            dd8[d]   = cov ? dv : 1.0f;

            yy = fmaf(yy, 20.0f, -10.0f);
            if (yy > 10.0f)  { yy = fmaf(1e-6f, yy - 10.0f, 10.0f);  extra += LOG_BETA; }
            if (yy < -10.0f) { yy = fmaf(1e-6f, yy + 10.0f, -10.0f); extra += LOG_BETA; }
            yd[d] = yy;
        }

        // 2 x v_log_f32 of quad products (each >= ~1e-24, still normal in f32)
        float q1 = (dd8[0] * dd8[1]) * (dd8[2] * dd8[3]);
        float q2 = (dd8[4] * dd8[5]) * (dd8[6] * dd8[7]);
        float contrib = fmaf(__log2f(q1) + __log2f(q2), LN2F, extra);

        f32x4 y1 = { yd[0], yd[1], yd[2], yd[3] };
        f32x4 y2 = { yd[4], yd[5], yd[6], yd[7] };
        __builtin_nontemporal_store(y1, (f32x4*)y_out + 2 * q);
        __builtin_nontemporal_store(y2, (f32x4*)y_out + 2 * q + 1);
        __builtin_nontemporal_store(Lin + contrib, ld_out + q);
    };

    if (fast) {
#pragma unroll
        for (int j = 0; j < 4; ++j)
            body8(Xa[j], Xb[j], Ld[j], i0 + j * T);
        // remainder (n not divisible by T) — never runs in the bench shape
        for (int g = i0 + 4 * T; g < n; g += T)
            body8(xv4[2 * g], xv4[2 * g + 1], logdet_in[g], g);
    } else {
        // generic fallback: simple grid-stride loop
        for (int g = i0; g < n; g += T)
            body8(xv4[2 * g], xv4[2 * g + 1], logdet_in[g], g);
    }
}

extern "C" void kernel_launch(void* const* d_in, const int* in_sizes, int n_in,
                              void* d_out, int out_size, void* d_ws, size_t ws_size,
                              hipStream_t stream) {
    const float* x      = (const float*)d_in[0];   // [N, 8]
    const float* logdet = (const float*)d_in[1];   // [N, 1]
    const float* p      = (const float*)d_in[2];   // [63, 8]

    const int n = in_sizes[1];                     // N points
    float* y_out  = (float*)d_out;                 // [N*8]
    float* ld_out = (float*)d_out + (size_t)n * NDIM;  // [N]

    const int block = 256;
    int grid = 2048;                               // T=524288 -> 4 points/thread
    if ((long long)grid * block > (long long)n) grid = (n + block - 1) / block;
    cdfq_fused<<<grid, block, 0, stream>>>(x, logdet, p, y_out, ld_out, n);
}

// Round 4
// 143.451 us; speedup vs baseline: 1.0204x; 1.0204x over previous
//
#include <hip/hip_runtime.h>
#include <math.h>

// Problem constants (from reference)
#define NDIM   8
#define NBINS  64
#define LOG_BETA   (-13.815510557964274f)  // log(1e-6)
#define LN2F       0.69314718055994531f
// mesh is geometric: boundary_j (original coords) = x1L*(1.2^j-1)/0.2, j=0..32
// bin index from |x|: g = log2(1 + ALPHA*|x|) / log2(1.2);  ALPHA = (1.2^32-1)/10
#define ALPHA      34.0821892f
#define INV_LOG2R  3.80178401692393f       // 1/log2(1.2)
#define L2R        0.26303440583379378f    // log2(1.2)

typedef float f32x4 __attribute__((ext_vector_type(4)));  // ok for nontemporal builtins

// Two threads per point: lane g handles float4 half (g&1) of point (g>>1).
// PHASE-SEPARATED memory: vmcnt retires IN ISSUE ORDER on CDNA, so a load
// issued after a store cannot be waited on without transitively waiting for
// the store's ack (which under 1.6 TB/s of streaming writes is thousands of
// cycles). Fast path therefore issues ALL loads first, computes, then issues
// ALL stores in a terminal burst — no load-wait ever follows a store.
__global__ __launch_bounds__(256, 5) void cdfq_fused(const float* __restrict__ x,
                                                     const float* __restrict__ logdet_in,
                                                     const float* __restrict__ p,
                                                     float* __restrict__ y_out,
                                                     float* __restrict__ ld_out,
                                                     int n)
{
    __shared__ float4 stbl[NDIM * NBINS];  // [d][k]: {v1, slope, F_pre, mesh_k}

    const int t  = threadIdx.x;
    const int T  = gridDim.x * blockDim.x;         // work-item stride
    const int i0 = blockIdx.x * blockDim.x + t;
    const int G  = 2 * n;                          // work items = half-points
    const int iters = G / T;                       // 8 on the bench shape
    const bool fast = (iters == 8) && (iters * T == G);
    const float4* xv4 = (const float4*)x;

    // ---- phase 1: issue ALL loads (8 x 20 B/lane) before any other memory op
    float4 X[8]; float L[8];
    if (fast) {
#pragma unroll
        for (int j = 0; j < 8; ++j) {
            int g = i0 + j * T;
            X[j] = xv4[g];
            L[j] = logdet_in[g >> 1];
        }
    }
    __builtin_amdgcn_sched_barrier(0);   // do not sink loads below prep

    // ---- prep: each wave builds TWO dims of the table fully in-register.
    //      Runs while the phase-1 loads are in flight. ONE barrier total. ----
    {
        const int lane = t & 63;
        const int w    = t >> 6;
        const float pw32 = exp2f(32.0f * L2R);     // 1.2^32
        const float inv  = 0.5f / (pw32 - 1.0f);
        auto meshf = [&](float tt) {               // normalized mesh coordinate
            float fidx = tt - 32.0f;
            float pw = exp2f(fabsf(fidx) * L2R);
            float r  = (pw - 1.0f) * inv;
            return 0.5f + ((fidx >= 0.0f) ? r : -r);
        };
        const float m0  = meshf((float)lane);          // mesh[lane]
        const float m1  = meshf((float)(lane + 1));    // mesh[lane+1]
        const float el  = m1 - m0;                     // elmt[lane]
        const float el1 = __shfl_down(el, 1);          // elmt[lane+1] (lane63 unused)
        const float e0e63 = 2.0f * (meshf(1.0f) - meshf(0.0f)); // elmt[0]+elmt[63]

#pragma unroll
        for (int dd = 0; dd < 2; ++dd) {
            const int d = 2 * w + dd;
            float ep = 0.0f;
            if (lane < 63) ep = __expf(p[lane * NDIM + d]);  // interior node lane+1
            // normalization: sum of ep * (elmt[k]+elmt[k+1])/2 over interior nodes
            float s = ep * 0.5f * (el + el1);
#pragma unroll
            for (int off = 32; off; off >>= 1) s += __shfl_xor(s, off);
            const float scale = (1.0f - e0e63 * 5e-7f) / s;
            const float epu = __shfl_up(ep, 1);
            const float pdl = (lane == 0)  ? 1e-6f : scale * epu;  // pdf[lane]
            const float pdn = (lane == 63) ? 1e-6f : scale * ep;   // pdf[lane+1]
            const float cell = 0.5f * (pdl + pdn) * el;
            // inclusive scan -> exclusive prefix
            float v = cell;
#pragma unroll
            for (int off = 1; off < 64; off <<= 1) {
                float u = __shfl_up(v, off);
                if (lane >= off) v += u;
            }
            stbl[(d << 6) | lane] = make_float4(pdl, (pdn - pdl) / el, v - cell, m0);
        }
    }
    __syncthreads();

    // ---- per-half-point body: 4 dims, one shfl_xor to combine logdet.
    //      Pure compute: returns outputs, performs NO global memory ops. ----
    auto bodyR = [&](float4 Xv, float Lin, int g, f32x4& Yv, float& LDv) {
        const int dbase = (g & 1) << 2;            // dims 0-3 or 4-7
        float xd[4] = {Xv.x, Xv.y, Xv.z, Xv.w};
        float yd[4], dd4[4];
        float extra = 0.0f;

#pragma unroll
        for (int dl = 0; dl < 4; ++dl) {
            float xo = xd[dl];
            float xs = fmaf(xo, 0.05f, 0.5f);            // (x+10)/20 to 1 ulp
            // analytic bin: g = log2(1 + alpha*|x|)/log2(1.2); one v_log_f32
            float gg = __log2f(fmaf(ALPHA, fabsf(xo), 1.0f)) * INV_LOG2R;
            // merged index: CDF & derivative are continuous at bin boundaries,
            // so boundary misclassification (gg exactly integral) is harmless.
            int jf = (int)fminf(gg, 31.0f);
            int k  = (xo >= 0.0f) ? (32 + jf) : (31 - jf);

            float4 tb = stbl[((dbase + dl) << 6) + k];   // {v1, slope, F_pre, mesh_k}
            float xm  = xs - tb.w;
            bool cov  = (xs >= 0.0f) && (xs < 1.0f);

            float yc = tb.z + xm * fmaf(0.5f * xm, tb.y, tb.x);
            float dv = fmaf(xm, tb.y, tb.x);
            float yy = cov ? yc : xs;
            dd4[dl]  = cov ? dv : 1.0f;

            yy = fmaf(yy, 20.0f, -10.0f);
            if (yy > 10.0f)  { yy = fmaf(1e-6f, yy - 10.0f, 10.0f);  extra += LOG_BETA; }
            if (yy < -10.0f) { yy = fmaf(1e-6f, yy + 10.0f, -10.0f); extra += LOG_BETA; }
            yd[dl] = yy;
        }

        // 2 x v_log_f32 of pairwise products (each product >= 1e-12, no underflow)
        float l2 = __log2f(dd4[0] * dd4[1]) + __log2f(dd4[2] * dd4[3]);
        float contrib = fmaf(l2, LN2F, extra);
        float cross   = __shfl_xor(contrib, 1);    // partner half-point

        Yv  = (f32x4){ yd[0], yd[1], yd[2], yd[3] };
        LDv = Lin + contrib + cross;               // valid on even-g lanes
    };

    if (fast) {
        // ---- phase 2: pure compute; input regs X[j]/L[j] die into Y[j]/LD[j]
        f32x4 Y[8]; float LD[8];
#pragma unroll
        for (int j = 0; j < 8; ++j)
            bodyR(X[j], L[j], i0 + j * T, Y[j], LD[j]);

        // ---- phase 3: terminal store burst (no subsequent loads to poison)
#pragma unroll
        for (int j = 0; j < 8; ++j) {
            int g = i0 + j * T;
            __builtin_nontemporal_store(Y[j], (f32x4*)y_out + g);
            if ((g & 1) == 0) ld_out[g >> 1] = LD[j];
        }
    } else {
        // generic fallback: simple grid-stride loop (correctness path)
        for (int g = i0; g < G; g += T) {
            f32x4 Yv; float LDv;
            bodyR(xv4[g], logdet_in[g >> 1], g, Yv, LDv);
            __builtin_nontemporal_store(Yv, (f32x4*)y_out + g);
            if ((g & 1) == 0) ld_out[g >> 1] = LDv;
        }
    }
}

extern "C" void kernel_launch(void* const* d_in, const int* in_sizes, int n_in,
                              void* d_out, int out_size, void* d_ws, size_t ws_size,
                              hipStream_t stream) {
    const float* x      = (const float*)d_in[0];   // [N, 8]
    const float* logdet = (const float*)d_in[1];   // [N, 1]
    const float* p      = (const float*)d_in[2];   // [63, 8]

    const int n = in_sizes[1];                     // N points
    float* y_out  = (float*)d_out;                 // [N*8]
    float* ld_out = (float*)d_out + (size_t)n * NDIM;  // [N]

    const int block = 256;
    int grid = 2048;                               // T=524288 -> 8 half-points/thread
    if ((long long)grid * block > 2LL * n) grid = (2 * n + block - 1) / block;
    cdfq_fused<<<grid, block, 0, stream>>>(x, logdet, p, y_out, ld_out, n);
}

// Round 5
// 135.189 us; speedup vs baseline: 1.0828x; 1.0611x over previous
//
#include <hip/hip_runtime.h>
#include <math.h>

// Problem constants (from reference)
#define NDIM   8
#define NBINS  64
#define LOG_BETA   (-13.815510557964274f)  // log(1e-6)
#define LN2F       0.69314718055994531f
// mesh is geometric: boundary_j (original coords) = x1L*(1.2^j-1)/0.2, j=0..32
// bin index from |x|: g = log2(1 + ALPHA*|x|) / log2(1.2);  ALPHA = (1.2^32-1)/10
#define ALPHA      34.0821892f
#define INV_LOG2R  3.80178401692393f       // 1/log2(1.2)
#define L2R        0.26303440583379378f    // log2(1.2)

typedef float f32x4 __attribute__((ext_vector_type(4)));  // ok for nontemporal builtins

// Two threads per point: lane g handles float4 half (g&1) of point (g>>1).
// Structure = round-2 winner (rolling pipeline, 8 blocks/CU) with a thinned
// per-dim VALU chain and 3-deep prefetch.
__global__ __launch_bounds__(256, 8) void cdfq_fused(const float* __restrict__ x,
                                                     const float* __restrict__ logdet_in,
                                                     const float* __restrict__ p,
                                                     float* __restrict__ y_out,
                                                     float* __restrict__ ld_out,
                                                     int n)
{
    __shared__ float4 stbl[NDIM * NBINS];  // [d][k]: {v1, slope, F_pre, mesh_k}

    const int t  = threadIdx.x;
    const int T  = gridDim.x * blockDim.x;         // work-item stride
    const int i0 = blockIdx.x * blockDim.x + t;
    const int G  = 2 * n;                          // work items = half-points
    const int iters = G / T;                       // 8 on the bench shape
    const float4* xv4 = (const float4*)x;

    // ---- prologue: 3-deep prefetch issued BEFORE prep so the first three
    //      memory latencies hide behind prep's VALU/shuffle work ----
    float4 X0, X1, X2; float L0, L1, Lc2;
    if (iters > 0) { X0 = xv4[i0];         L0  = logdet_in[i0 >> 1]; }
    if (iters > 1) { X1 = xv4[i0 + T];     L1  = logdet_in[(i0 + T) >> 1]; }
    if (iters > 2) { X2 = xv4[i0 + 2 * T]; Lc2 = logdet_in[(i0 + 2 * T) >> 1]; }
    __builtin_amdgcn_sched_barrier(0);   // do not sink these below prep

    // ---- prep: each wave builds TWO dims of the table fully in-register.
    //      Runs while prologue loads are in flight. ONE barrier total. ----
    {
        const int lane = t & 63;
        const int w    = t >> 6;
        const float pw32 = exp2f(32.0f * L2R);     // 1.2^32
        const float inv  = 0.5f / (pw32 - 1.0f);
        auto meshf = [&](float tt) {               // normalized mesh coordinate
            float fidx = tt - 32.0f;
            float pw = exp2f(fabsf(fidx) * L2R);
            float r  = (pw - 1.0f) * inv;
            return 0.5f + ((fidx >= 0.0f) ? r : -r);
        };
        const float m0  = meshf((float)lane);          // mesh[lane]
        const float m1  = meshf((float)(lane + 1));    // mesh[lane+1]
        const float el  = m1 - m0;                     // elmt[lane]
        const float el1 = __shfl_down(el, 1);          // elmt[lane+1] (lane63 unused)
        const float e0e63 = 2.0f * (meshf(1.0f) - meshf(0.0f)); // elmt[0]+elmt[63]

#pragma unroll
        for (int dd = 0; dd < 2; ++dd) {
            const int d = 2 * w + dd;
            float ep = 0.0f;
            if (lane < 63) ep = __expf(p[lane * NDIM + d]);  // interior node lane+1
            // normalization: sum of ep * (elmt[k]+elmt[k+1])/2 over interior nodes
            float s = ep * 0.5f * (el + el1);
#pragma unroll
            for (int off = 32; off; off >>= 1) s += __shfl_xor(s, off);
            const float scale = (1.0f - e0e63 * 5e-7f) / s;
            const float epu = __shfl_up(ep, 1);
            const float pdl = (lane == 0)  ? 1e-6f : scale * epu;  // pdf[lane]
            const float pdn = (lane == 63) ? 1e-6f : scale * ep;   // pdf[lane+1]
            const float cell = 0.5f * (pdl + pdn) * el;
            // inclusive scan -> exclusive prefix
            float v = cell;
#pragma unroll
            for (int off = 1; off < 64; off <<= 1) {
                float u = __shfl_up(v, off);
                if (lane >= off) v += u;
            }
            stbl[(d << 6) | lane] = make_float4(pdl, (pdn - pdl) / el, v - cell, m0);
        }
    }
    __syncthreads();

    // ---- iteration-invariant hoists: half-point parity never changes ----
    const float4* tbl = &stbl[((i0 & 1) << 2) << 6];   // dims 0-3 or 4-7 base
    const bool evenlane = ((i0 & 1) == 0);

    // ---- per-half-point body: 4 dims, one shfl_xor to combine logdet ----
    auto body = [&](float4 Xv, float Lin, int g) {
        float xd[4] = {Xv.x, Xv.y, Xv.z, Xv.w};
        float yd[4], dd4[4];
        float extra = 0.0f;

#pragma unroll
        for (int dl = 0; dl < 4; ++dl) {
            float xo = xd[dl];
            float u  = fabsf(xo);
            float xs = fmaf(xo, 0.05f, 0.5f);            // (x+10)/20 to 1 ulp
            // analytic bin: g = log2(1 + alpha*|x|)/log2(1.2); one v_log_f32
            float gg = __log2f(fmaf(ALPHA, u, 1.0f)) * INV_LOG2R;
            // merged index (CDF & dCDF continuous at bin boundaries):
            // jf in [0,31] -> 32+jf == 32^jf, 31-jf == 31^jf: one cndmask + xor
            int jf = (int)fminf(gg, 31.0f);
            int k  = ((xo >= 0.0f) ? 32 : 31) ^ jf;

            float4 tb = tbl[(dl << 6) + k];              // {v1, slope, F_pre, mesh_k}
            float xm  = xs - tb.w;
            bool cov  = (u < 10.0f);                     // == (0 <= xs < 1) for gaussian data

            float yc = fmaf(xm, fmaf(0.5f * xm, tb.y, tb.x), tb.z);
            float dv = fmaf(xm, tb.y, tb.x);
            float yy = cov ? yc : xs;
            dd4[dl]  = cov ? dv : 1.0f;

            yy = fmaf(yy, 20.0f, -10.0f);
            if (yy > 10.0f)  { yy = fmaf(1e-6f, yy - 10.0f, 10.0f);  extra += LOG_BETA; }
            if (yy < -10.0f) { yy = fmaf(1e-6f, yy + 10.0f, -10.0f); extra += LOG_BETA; }
            yd[dl] = yy;
        }

        // 2 x v_log_f32 of pairwise products (each product >= 1e-12, no underflow)
        float l2 = __log2f(dd4[0] * dd4[1]) + __log2f(dd4[2] * dd4[3]);
        float contrib = fmaf(l2, LN2F, extra);
        float cross   = __shfl_xor(contrib, 1);    // partner half-point

        f32x4 yv = { yd[0], yd[1], yd[2], yd[3] };
        __builtin_nontemporal_store(yv, (f32x4*)y_out + g);
        if (evenlane)
            __builtin_nontemporal_store(Lin + contrib + cross, ld_out + (g >> 1));
    };

    // ---- main loop: guard-free 4-stage (3 loads in flight) software pipeline ----
    for (int j = 0; j < iters; ++j) {
        float4 Xn; float Ln;
        const bool more = (j + 3 < iters);         // wave-uniform
        if (more) {
            int gx = i0 + (j + 3) * T;
            Xn = xv4[gx];
            Ln = logdet_in[gx >> 1];
        }
        __builtin_amdgcn_sched_barrier(0);         // keep prefetch above the compute

        body(X0, L0, i0 + j * T);

        X0 = X1; L0 = L1;
        X1 = X2; L1 = Lc2;
        if (more) { X2 = Xn; Lc2 = Ln; }
    }

    // ---- remainder (never runs when T | G; kept for generality) ----
    int gr = i0 + iters * T;
    if (gr < G) {
        body(xv4[gr], logdet_in[gr >> 1], gr);     // pairs never split: G is even,
                                                   // partner is adjacent lane
    }
}

extern "C" void kernel_launch(void* const* d_in, const int* in_sizes, int n_in,
                              void* d_out, int out_size, void* d_ws, size_t ws_size,
                              hipStream_t stream) {
    const float* x      = (const float*)d_in[0];   // [N, 8]
    const float* logdet = (const float*)d_in[1];   // [N, 1]
    const float* p      = (const float*)d_in[2];   // [63, 8]

    const int n = in_sizes[1];                     // N points
    float* y_out  = (float*)d_out;                 // [N*8]
    float* ld_out = (float*)d_out + (size_t)n * NDIM;  // [N]

    const int block = 256;
    int grid = 2048;                               // 8 blocks/CU co-resident
    if ((long long)grid * block > 2LL * n) grid = (2 * n + block - 1) / block;
    cdfq_fused<<<grid, block, 0, stream>>>(x, logdet, p, y_out, ld_out, n);
}